// Round 2
// baseline (13226.289 us; speedup 1.0000x reference)
//
#include <hip/hip_runtime.h>

// ---------------------------------------------------------------------------
// Persistent weight-stationary LSTM, bf16 MFMA, flag-based dataflow sync.
// T=1024 B=64 C=256 H=512, 2 layers, fp32 in/out.
//  - 256 blocks x 256 threads, 1 block/CU; blocks 0..127 = layer0,
//    128..255 = layer1. NO grid barrier: per-block monotonic progress flags
//    (relaxed agent-scope = MALL-coherent), depth-4 h rings so layer0 runs
//    ahead of layer1. Per-tick critical path = store-ack -> flag -> wave-wide
//    poll detect -> h load -> compute (~4 MALL RTTs, was ~6+ with barrier tree).
//  - Weights bf16, packed once into MFMA B-frag order, held in VGPRs all run.
//  - h state bf16 in MALL-coherent ring; c state lives in a register.
//  - Layer0's x-projection MFMAs run BEFORE the flag wait (independent work).
// ---------------------------------------------------------------------------

#define TT 1024
#define BB 64
#define CC 256
#define HH 512
#define Y_ELEMS (TT * BB * HH)
#define S_ELEMS (BB * HH)
#define RING 4

typedef __attribute__((ext_vector_type(8))) short bf16x8;
typedef __attribute__((ext_vector_type(4))) float f32x4;
typedef unsigned int u32;
typedef unsigned short u16;
typedef unsigned long long u64;

// ---- ws layout (bytes) ----
#define WS_FLAG 0          // 256 u32 progress flags (flag[bid] = ticks done)
#define WS_BSUM0 4096      // 2048 f32
#define WS_BSUM1 12288     // 2048 f32
#define WS_H0 20480        // RING * 65536 B (h0 ring, bf16)
#define WS_H1 282624       // RING * 65536 B (h1 ring, bf16)
#define WS_WPK0 544768     // 128*24*64*8 bf16  (layer0 packed W) = 3145728 B
#define WS_WPK1 3690496    // 128*32*64*8 bf16  (layer1 packed W) = 4194304 B
// end 7884800 (~7.9 MB)

__device__ __forceinline__ u16 f2b_rne(float f) {
    u32 u = __float_as_uint(f);
    return (u16)((u + 0x7FFFu + ((u >> 16) & 1u)) >> 16);
}
__device__ __forceinline__ u16 f2b_fast(float f) {  // round-half-up, 2 ops
    return (u16)((__float_as_uint(f) + 0x8000u) >> 16);
}
__device__ __forceinline__ float sigf(float z) { return 1.0f / (1.0f + __expf(-z)); }
__device__ __forceinline__ float tanh_f(float z) { return 2.0f / (1.0f + __expf(-2.0f * z)) - 1.0f; }

__device__ __forceinline__ bf16x8 pack8(float4 a, float4 b) {
    union { u16 u[8]; bf16x8 v; } r;
    r.u[0] = f2b_fast(a.x); r.u[1] = f2b_fast(a.y); r.u[2] = f2b_fast(a.z); r.u[3] = f2b_fast(a.w);
    r.u[4] = f2b_fast(b.x); r.u[5] = f2b_fast(b.y); r.u[6] = f2b_fast(b.z); r.u[7] = f2b_fast(b.w);
    return r.v;
}

// ---- coherence-point (MALL) accessors: relaxed agent scope => sc0|sc1
//      bypass, per-element cross-XCD coherent, NO cache-wide flush/inv ----
__device__ __forceinline__ u64 cload64(const u64* p) {
    return __hip_atomic_load((u64*)p, __ATOMIC_RELAXED, __HIP_MEMORY_SCOPE_AGENT);
}
__device__ __forceinline__ void cstore32(u32* p, u32 v) {
    __hip_atomic_store(p, v, __ATOMIC_RELAXED, __HIP_MEMORY_SCOPE_AGENT);
}
__device__ __forceinline__ u32 cload32(const u32* p) {
    return __hip_atomic_load((u32*)p, __ATOMIC_RELAXED, __HIP_MEMORY_SCOPE_AGENT);
}

// Wave-wide flag wait: lane L checks flags[4L..4L+3]; lanes 0..31 cover the
// 128 layer0 flags (threshold thrL0), lanes 32..63 the layer1 flags (thrL1).
// Detection = one MALL RTT after the last relevant flag lands.
__device__ __forceinline__ void wait_flags(const u32* flags, int lane, u32 thrL0, u32 thrL1) {
    const u32* p = flags + lane * 4;
    const u32 thr = (lane < 32) ? thrL0 : thrL1;
    for (;;) {
        u32 a = cload32(p + 0), b = cload32(p + 1);
        u32 c = cload32(p + 2), d = cload32(p + 3);
        u32 m = a < b ? a : b;
        u32 n = c < d ? c : d;
        m = m < n ? m : n;
        if (__all((int)(m >= thr))) break;
        __builtin_amdgcn_s_sleep(1);
    }
    asm volatile("" ::: "memory");  // keep h loads below the flag check
}

// ---- init: zero flags, bsum = bih+bhh, h ring slot (RING-1) <- bf16(h init) ----
__global__ void k_init(const float* __restrict__ bih0, const float* __restrict__ bhh0,
                       const float* __restrict__ bih1, const float* __restrict__ bhh1,
                       const float* __restrict__ h00, const float* __restrict__ h01,
                       unsigned char* __restrict__ ws) {
    u32* flg = (u32*)(ws + WS_FLAG);
    float* bs0 = (float*)(ws + WS_BSUM0);
    float* bs1 = (float*)(ws + WS_BSUM1);
    u16* h0 = (u16*)(ws + WS_H0) + (RING - 1) * S_ELEMS;
    u16* h1 = (u16*)(ws + WS_H1) + (RING - 1) * S_ELEMS;
    int t = blockIdx.x * 256 + threadIdx.x;  // 32768 threads
    if (t < 256) flg[t] = 0u;
    if (t < 2048) { bs0[t] = bih0[t] + bhh0[t]; bs1[t] = bih1[t] + bhh1[t]; }
    if (t < S_ELEMS) { h0[t] = f2b_rne(h00[t]); h1[t] = f2b_rne(h01[t]); }
}

// ---- weight pack: fp32 [4H,K] -> bf16 B-frag order wpk[bidL][kt][lane][8] ----
// rows permuted: n-index (lane&15) = gg*4+jj  <->  W row = gg*512 + bidL*4 + jj
__global__ void k_wprep(const float* __restrict__ Wih0, const float* __restrict__ Whh0,
                        const float* __restrict__ Wih1, const float* __restrict__ Whh1,
                        unsigned char* __restrict__ ws) {
    u16* wpk0 = (u16*)(ws + WS_WPK0);
    u16* wpk1 = (u16*)(ws + WS_WPK1);
    int u = blockIdx.x * 256 + threadIdx.x;  // 458752 threads
    const float* s;
    u16* d;
    if (u < 128 * 24 * 64) {  // layer0: 8 x-tiles (K=256) + 16 h-tiles (K=512)
        int bidL = u / (24 * 64);
        int kt = (u >> 6) % 24;
        int lane = u & 63;
        int n = lane & 15, quad = lane >> 4;
        int row = (n >> 2) * 512 + bidL * 4 + (n & 3);
        int k = kt * 32 + quad * 8;
        s = (k < 256) ? (Wih0 + (size_t)row * 256 + k) : (Whh0 + (size_t)row * 512 + (k - 256));
        d = wpk0 + (size_t)((bidL * 24 + kt) * 64 + lane) * 8;
    } else {  // layer1: 16 y0-tiles + 16 h1-tiles (K=1024)
        int v = u - 128 * 24 * 64;
        int bidL = v / (32 * 64);
        int kt = (v >> 6) % 32;
        int lane = v & 63;
        int n = lane & 15, quad = lane >> 4;
        int row = (n >> 2) * 512 + bidL * 4 + (n & 3);
        int k = kt * 32 + quad * 8;
        s = (k < 512) ? (Wih1 + (size_t)row * 512 + k) : (Whh1 + (size_t)row * 512 + (k - 512));
        d = wpk1 + (size_t)((bidL * 32 + kt) * 64 + lane) * 8;
    }
    #pragma unroll
    for (int i = 0; i < 8; ++i) d[i] = f2b_rne(s[i]);
}

// ---- the persistent tick loop, templated on layer ----
// Dependency protocol (flag[b] = ticks completed by block b):
//   L0 tick t: needs all L0 flags >= t        (h0[t-1] written)
//              and all L1 flags >= t-RING+1   (ring slot t%RING free of L1 readers)
//   L1 tick t: needs all L0 flags >= t+1      (y0[t] = h0 tick-t output written)
//              and all L1 flags >= t          (h1[t-1] written; slot-free implied)
template <int LAYER>
__device__ void run_ticks(const float* __restrict__ x, const float* __restrict__ c0,
                          float* __restrict__ out, unsigned char* __restrict__ ws,
                          int bidL, int bid) {
    constexpr int NKT = (LAYER == 0) ? 24 : 32;
    u32* flags = (u32*)(ws + WS_FLAG);
    const float* bs = (const float*)(ws + (LAYER == 0 ? WS_BSUM0 : WS_BSUM1));
    u16* h0r = (u16*)(ws + WS_H0);
    u16* h1r = (u16*)(ws + WS_H1);
    const u16* wpk = (const u16*)(ws + (LAYER == 0 ? WS_WPK0 : WS_WPK1));

    const int tid = threadIdx.x, lane = tid & 63, wave = tid >> 6;
    const int r16 = lane & 15, quad = lane >> 4, q8 = quad * 8;
    const int gg = r16 >> 2, jj = r16 & 3;
    const int b0 = wave * 16;
    const int col = bidL * 4 + jj;            // h column this lane finalizes
    const int myb = b0 + quad * 4 + gg;       // batch this lane finalizes
    const int sl0 = (quad << 4) | (0 << 2) | jj;
    const int sl1 = (quad << 4) | (1 << 2) | jj;
    const int sl2 = (quad << 4) | (2 << 2) | jj;
    const int sl3 = (quad << 4) | (3 << 2) | jj;

    // biases (hoisted), c state in register for the whole run
    const float bi = bs[0 * HH + col], bf_ = bs[1 * HH + col];
    const float bg = bs[2 * HH + col], bo = bs[3 * HH + col];
    float c = c0[myb * HH + col];

    // weight fragments: resident in VGPRs for all 1024 ticks
    bf16x8 w[NKT];
    {
        const u16* wp = wpk + (size_t)(bidL * NKT * 64 + lane) * 8;
        #pragma unroll
        for (int kt = 0; kt < NKT; ++kt) w[kt] = *(const bf16x8*)(wp + (size_t)kt * 64 * 8);
    }

    for (int t = 0; t < TT; ++t) {
        f32x4 aE = {0.f, 0.f, 0.f, 0.f}, aO = {0.f, 0.f, 0.f, 0.f};
        if (LAYER == 0) {
            // x projection FIRST: independent of the recurrence -> overlaps
            // other blocks' flag publication. fp32 -> bf16 (half-up) in flight.
            const float* xp = x + ((size_t)t * BB + b0 + r16) * CC + q8;
            #pragma unroll
            for (int kt = 0; kt < 8; ++kt) {
                float4 f0 = *(const float4*)(xp + kt * 32);
                float4 f1 = *(const float4*)(xp + kt * 32 + 4);
                bf16x8 a = pack8(f0, f1);
                if (kt & 1) aO = __builtin_amdgcn_mfma_f32_16x16x32_bf16(a, w[kt], aO, 0, 0, 0);
                else        aE = __builtin_amdgcn_mfma_f32_16x16x32_bf16(a, w[kt], aE, 0, 0, 0);
            }
            if (t > 0) {
                u32 thr1 = (t >= RING) ? (u32)(t - RING + 1) : 0u;
                wait_flags(flags, lane, (u32)t, thr1);
            }
            // recurrent: h0[t-1] at ring slot (t-1)%RING — coherence-point loads
            const u64* hp = (const u64*)(h0r + ((t + RING - 1) & (RING - 1)) * S_ELEMS
                                             + (size_t)(b0 + r16) * HH + q8);
            #pragma unroll
            for (int kt = 0; kt < 16; ++kt) {
                union { u64 q[2]; bf16x8 v; } au;
                au.q[0] = cload64(hp + kt * 8);
                au.q[1] = cload64(hp + kt * 8 + 1);
                if (kt & 1) aO = __builtin_amdgcn_mfma_f32_16x16x32_bf16(au.v, w[8 + kt], aO, 0, 0, 0);
                else        aE = __builtin_amdgcn_mfma_f32_16x16x32_bf16(au.v, w[8 + kt], aE, 0, 0, 0);
            }
        } else {
            wait_flags(flags, lane, (u32)(t + 1), (u32)t);
            // y0[t] at h0 ring slot t%RING; h1[t-1] at slot (t-1)%RING
            const u64* pa = (const u64*)(h0r + (t & (RING - 1)) * S_ELEMS
                                             + (size_t)(b0 + r16) * HH + q8);
            const u64* pb = (const u64*)(h1r + ((t + RING - 1) & (RING - 1)) * S_ELEMS
                                             + (size_t)(b0 + r16) * HH + q8);
            #pragma unroll
            for (int kt = 0; kt < 16; ++kt) {
                union { u64 q[2]; bf16x8 v; } au;
                au.q[0] = cload64(pa + kt * 8);
                au.q[1] = cload64(pa + kt * 8 + 1);
                if (kt & 1) aO = __builtin_amdgcn_mfma_f32_16x16x32_bf16(au.v, w[kt], aO, 0, 0, 0);
                else        aE = __builtin_amdgcn_mfma_f32_16x16x32_bf16(au.v, w[kt], aE, 0, 0, 0);
            }
            #pragma unroll
            for (int kt = 0; kt < 16; ++kt) {
                union { u64 q[2]; bf16x8 v; } au;
                au.q[0] = cload64(pb + kt * 8);
                au.q[1] = cload64(pb + kt * 8 + 1);
                if (kt & 1) aO = __builtin_amdgcn_mfma_f32_16x16x32_bf16(au.v, w[16 + kt], aO, 0, 0, 0);
                else        aE = __builtin_amdgcn_mfma_f32_16x16x32_bf16(au.v, w[16 + kt], aE, 0, 0, 0);
            }
        }
        f32x4 acc = aE + aO;

        // gather the 4 gates for (myb, col): lanes sharing (quad,jj), gg = gate
        float gi = 0.f, gf = 0.f, gc = 0.f, go = 0.f;
        #pragma unroll
        for (int r = 0; r < 4; ++r) {
            float v0 = __shfl(acc[r], sl0, 64);
            float v1 = __shfl(acc[r], sl1, 64);
            float v2 = __shfl(acc[r], sl2, 64);
            float v3 = __shfl(acc[r], sl3, 64);
            if (r == gg) { gi = v0; gf = v1; gc = v2; go = v3; }
        }
        gi = sigf(gi + bi);
        gf = sigf(gf + bf_);
        gc = tanh_f(gc + bg);
        go = sigf(go + bo);
        c = gf * c + gi * gc;
        float h = go * tanh_f(c);

        // h store: pair adjacent-jj lanes into one u32 coherence-point store
        u16* hw = (LAYER == 0 ? h0r : h1r) + (t & (RING - 1)) * S_ELEMS;
        u32 hb = (u32)f2b_rne(h);
        u32 partner = __shfl_xor(hb, 1, 64);
        if ((jj & 1) == 0)
            cstore32((u32*)(hw + (size_t)myb * HH + col), hb | (partner << 16));
        if (LAYER == 1) out[(size_t)t * S_ELEMS + myb * HH + col] = h;
        if (t == TT - 1) {
            float* fin = out + Y_ELEMS + (LAYER == 0 ? 0 : 2) * S_ELEMS;
            fin[myb * HH + col] = h;
            fin[S_ELEMS + myb * HH + col] = c;
        }

        // publish: __syncthreads drains every wave's vmcnt (h stores at MALL),
        // then thread0's flag store is safely ordered after the data.
        __syncthreads();
        if (tid == 0) cstore32(&flags[bid], (u32)(t + 1));
    }
}

__global__ __launch_bounds__(256) void k_lstm(const float* __restrict__ x,
                                              const float* __restrict__ c00,
                                              const float* __restrict__ c01,
                                              float* __restrict__ out,
                                              unsigned char* __restrict__ ws) {
    const int bid = blockIdx.x;
    if (bid < 128) run_ticks<0>(x, c00, out, ws, bid, bid);
    else           run_ticks<1>(x, c01, out, ws, bid - 128, bid);
}

extern "C" void kernel_launch(void* const* d_in, const int* in_sizes, int n_in,
                              void* d_out, int out_size, void* d_ws, size_t ws_size,
                              hipStream_t stream) {
    const float* x    = (const float*)d_in[0];
    const float* h0_0 = (const float*)d_in[1];
    const float* c0_0 = (const float*)d_in[2];
    const float* h0_1 = (const float*)d_in[3];
    const float* c0_1 = (const float*)d_in[4];
    const float* Wih0 = (const float*)d_in[5];
    const float* Whh0 = (const float*)d_in[6];
    const float* bih0 = (const float*)d_in[7];
    const float* bhh0 = (const float*)d_in[8];
    const float* Wih1 = (const float*)d_in[9];
    const float* Whh1 = (const float*)d_in[10];
    const float* bih1 = (const float*)d_in[11];
    const float* bhh1 = (const float*)d_in[12];
    float* out = (float*)d_out;
    unsigned char* ws = (unsigned char*)d_ws;

    k_init<<<128, 256, 0, stream>>>(bih0, bhh0, bih1, bhh1, h0_0, h0_1, ws);
    k_wprep<<<1792, 256, 0, stream>>>(Wih0, Whh0, Wih1, Whh1, ws);
    k_lstm<<<256, 256, 0, stream>>>(x, c0_0, c0_1, out, ws);
}

// Round 4
// 6732.487 us; speedup vs baseline: 1.9645x; 1.9645x over previous
//
#include <hip/hip_runtime.h>

// ---------------------------------------------------------------------------
// Persistent weight-stationary LSTM, bf16 MFMA, decoupled per-layer sync.
// T=1024 B=64 C=256 H=512, 2 layers, fp32 in/out.
//  - 128 blocks x 256 threads: blocks 0..63 = layer0, 64..127 = layer1.
//    Block = 2 M-tiles (32 batches) x 4 column-groups; wave = 1 cg, full K.
//  - A-operands staged ONCE per block per tick into LDS (reg-staging via
//    relaxed agent loads = MALL-coherent, proven r1/r2), shared by 4 waves.
//    Row pitch 520 u16 (1040B) => ds_read_b128 at the 8-cycle bank floor.
//  - Sync: per-layer monotonic group counters (8 groups x 8 blocks), one
//    wave-wide poll covers both layers. No barrier tree, no resets, no ABA.
//    h0 ring depth 4 decouples L1 from L0 (L1 trails, absorbs stragglers).
//  - Weights bf16 in VGPRs all run (L0: 24 frags/wave, L1: 32 frags/wave).
//  - h stores packed to u64 (4 cols) to cut MALL write amplification.
// ---------------------------------------------------------------------------

#define TT 1024
#define BB 64
#define CC 256
#define HH 512
#define Y_ELEMS (TT * BB * HH)
#define S_ELEMS (BB * HH)
#define RING 4

typedef __attribute__((ext_vector_type(8))) short bf16x8;
typedef __attribute__((ext_vector_type(4))) float f32x4;
typedef unsigned int u32;
typedef unsigned short u16;
typedef unsigned long long u64;

// ---- ws layout (bytes) ----
#define WS_CNT   0         // 16 counter lines * 64B: [0..7]=L0 groups, [8..15]=L1
#define WS_BSUM0 4096      // 2048 f32
#define WS_BSUM1 12288     // 2048 f32
#define WS_H0R   20480     // RING * 65536 B (h0 ring, bf16; doubles as y0 feed)
#define WS_H1R   282624    // 2 * 65536 B  (h1 ping-pong, bf16)
#define WS_WPK0  413696    // 128*24*64*8 bf16 = 3145728 B
#define WS_WPK1  3559424   // 128*32*64*8 bf16 = 4194304 B
// end 7753728 (~7.75 MB)

__device__ __forceinline__ u16 f2b_rne(float f) {
    u32 u = __float_as_uint(f);
    return (u16)((u + 0x7FFFu + ((u >> 16) & 1u)) >> 16);
}
__device__ __forceinline__ u16 f2b_fast(float f) {  // round-half-up, 2 ops
    return (u16)((__float_as_uint(f) + 0x8000u) >> 16);
}
__device__ __forceinline__ float sigf(float z) { return 1.0f / (1.0f + __expf(-z)); }
__device__ __forceinline__ float tanh_f(float z) { return 2.0f / (1.0f + __expf(-2.0f * z)) - 1.0f; }

__device__ __forceinline__ bf16x8 pack8(float4 a, float4 b) {
    union { u16 u[8]; bf16x8 v; } r;
    r.u[0] = f2b_fast(a.x); r.u[1] = f2b_fast(a.y); r.u[2] = f2b_fast(a.z); r.u[3] = f2b_fast(a.w);
    r.u[4] = f2b_fast(b.x); r.u[5] = f2b_fast(b.y); r.u[6] = f2b_fast(b.z); r.u[7] = f2b_fast(b.w);
    return r.v;
}

// ---- MALL (agent, relaxed) accessors: the ONLY cross-block primitives ----
__device__ __forceinline__ u64 cload64(const u64* p) {
    return __hip_atomic_load((u64*)p, __ATOMIC_RELAXED, __HIP_MEMORY_SCOPE_AGENT);
}
__device__ __forceinline__ u32 cload32(const u32* p) {
    return __hip_atomic_load((u32*)p, __ATOMIC_RELAXED, __HIP_MEMORY_SCOPE_AGENT);
}
__device__ __forceinline__ void cstore64(u64* p, u64 v) {
    __hip_atomic_store(p, v, __ATOMIC_RELAXED, __HIP_MEMORY_SCOPE_AGENT);
}
__device__ __forceinline__ u32 cadd32(u32* p, u32 v) {
    return __hip_atomic_fetch_add(p, v, __ATOMIC_RELAXED, __HIP_MEMORY_SCOPE_AGENT);
}

// One wave-wide poll for BOTH layers' group counters (16 lines, 64B apart).
// Counters are monotonic (+1 per block per tick, 8 blocks/group): "all layer-L
// blocks finished tick T" <=> each of its 8 group counters >= 8T.
__device__ __forceinline__ void poll2(const u32* cnt, u32 need0, u32 need1) {
    const int lane = threadIdx.x & 63;
    const u32* p = cnt + lane * 16;
    const u32 need = (lane < 8) ? need0 : need1;
    for (;;) {
        int ok = (lane < 16) ? (int)(cload32(p) >= need) : 1;
        if (__all(ok)) break;
        __builtin_amdgcn_s_sleep(1);
    }
    asm volatile("" ::: "memory");  // keep staging loads below the poll
}

// Gate epilogue: gather i,f,g,o for this lane's (batch,col) via shuffles.
__device__ __forceinline__ float lstm_cell(const f32x4 acc, int sl0, int sl1, int sl2, int sl3,
                                           int gg, float bi, float bf_, float bg_, float bo,
                                           float& c) {
    float gi = 0.f, gf = 0.f, gc = 0.f, go = 0.f;
    #pragma unroll
    for (int r = 0; r < 4; ++r) {
        float v0 = __shfl(acc[r], sl0, 64);
        float v1 = __shfl(acc[r], sl1, 64);
        float v2 = __shfl(acc[r], sl2, 64);
        float v3 = __shfl(acc[r], sl3, 64);
        if (r == gg) { gi = v0; gf = v1; gc = v2; go = v3; }
    }
    gi = sigf(gi + bi);
    gf = sigf(gf + bf_);
    gc = tanh_f(gc + bg_);
    go = sigf(go + bo);
    c = gf * c + gi * gc;
    return go * tanh_f(c);
}

// ---- init: zero counters, bsum = bih+bhh, h inits into ring slots ----
__global__ void k_init(const float* __restrict__ bih0, const float* __restrict__ bhh0,
                       const float* __restrict__ bih1, const float* __restrict__ bhh1,
                       const float* __restrict__ h00, const float* __restrict__ h01,
                       unsigned char* __restrict__ ws) {
    float* bs0 = (float*)(ws + WS_BSUM0);
    float* bs1 = (float*)(ws + WS_BSUM1);
    u16* h0 = (u16*)(ws + WS_H0R) + (RING - 1) * S_ELEMS;  // tick 0 reads slot 3
    u16* h1 = (u16*)(ws + WS_H1R) + S_ELEMS;               // tick 0 reads slot 1
    int t = blockIdx.x * 256 + threadIdx.x;  // 32768 threads
    if (t < 256) ((u32*)ws)[t] = 0u;
    if (t < 2048) { bs0[t] = bih0[t] + bhh0[t]; bs1[t] = bih1[t] + bhh1[t]; }
    if (t < S_ELEMS) { h0[t] = f2b_rne(h00[t]); h1[t] = f2b_rne(h01[t]); }
}

// ---- weight pack: fp32 [4H,K] -> bf16 B-frag order wpk[cg][kt][lane][8] ----
// rows permuted: n-index (lane&15) = gg*4+jj  <->  W row = gg*512 + cg*4 + jj
// layer0: kt 0..7 = Wih0, 8..23 = Whh0. layer1: kt 0..15 = Wih1, 16..31 = Whh1.
__global__ void k_wprep(const float* __restrict__ Wih0, const float* __restrict__ Whh0,
                        const float* __restrict__ Wih1, const float* __restrict__ Whh1,
                        unsigned char* __restrict__ ws) {
    u16* wpk0 = (u16*)(ws + WS_WPK0);
    u16* wpk1 = (u16*)(ws + WS_WPK1);
    int u = blockIdx.x * 256 + threadIdx.x;  // 458752 threads
    const float* s;
    u16* d;
    if (u < 128 * 24 * 64) {
        int cg = u / (24 * 64);
        int kt = (u >> 6) % 24;
        int lane = u & 63;
        int n = lane & 15, quad = lane >> 4;
        int row = (n >> 2) * 512 + cg * 4 + (n & 3);
        int k = kt * 32 + quad * 8;
        s = (k < 256) ? (Wih0 + (size_t)row * 256 + k) : (Whh0 + (size_t)row * 512 + (k - 256));
        d = wpk0 + (size_t)((cg * 24 + kt) * 64 + lane) * 8;
    } else {
        int v = u - 128 * 24 * 64;
        int cg = v / (32 * 64);
        int kt = (v >> 6) % 32;
        int lane = v & 63;
        int n = lane & 15, quad = lane >> 4;
        int row = (n >> 2) * 512 + cg * 4 + (n & 3);
        int k = kt * 32 + quad * 8;
        s = (k < 512) ? (Wih1 + (size_t)row * 512 + k) : (Whh1 + (size_t)row * 512 + (k - 512));
        d = wpk1 + (size_t)((cg * 32 + kt) * 64 + lane) * 8;
    }
    #pragma unroll
    for (int i = 0; i < 8; ++i) d[i] = f2b_rne(s[i]);
}

// ---- dependency protocol (per-layer counters, monotonic) ----
//  L0 tick t: all L0 >= t (h0[t-1] written); t>=4: all L1 >= t-3 (ring slot free)
//  L1 tick t: all L0 >= t+1 (y0[t] written); all L1 >= t (h1[t-1] written)

// ============================ layer 0 ======================================
__device__ void run_l0(const float* __restrict__ x, const float* __restrict__ c0,
                       float* __restrict__ out, unsigned char* __restrict__ ws,
                       int bid, u16* smem) {
    u32* cnt = (u32*)(ws + WS_CNT);
    const float* bs = (const float*)(ws + WS_BSUM0);
    u16* h0r = (u16*)(ws + WS_H0R);
    const u16* wpk = (const u16*)(ws + WS_WPK0);

    const int tid = threadIdx.x, lane = tid & 63, wv = tid >> 6;
    const int mg = bid & 1;               // M-group: batches mg*32 .. mg*32+31
    const int cg = (bid >> 1) * 4 + wv;   // this wave's column-group (0..127)
    const int r16 = lane & 15, quad = lane >> 4, q8 = quad * 8;
    const int gg = r16 >> 2, jj = r16 & 3;
    const int sl0 = (quad << 4) | jj, sl1 = sl0 | 4, sl2 = sl0 | 8, sl3 = sl0 | 12;
    const int col = cg * 4 + jj;

    const float bi = bs[0 * HH + col], bff = bs[1 * HH + col];
    const float bgc = bs[2 * HH + col], bo = bs[3 * HH + col];
    float c[2];
    #pragma unroll
    for (int mt = 0; mt < 2; ++mt)
        c[mt] = c0[(mg * 32 + mt * 16 + quad * 4 + gg) * HH + col];

    bf16x8 w[24];
    {
        const u16* wp = wpk + (size_t)(cg * 24 * 64 + lane) * 8;
        #pragma unroll
        for (int kt = 0; kt < 24; ++kt) w[kt] = *(const bf16x8*)(wp + (size_t)kt * 64 * 8);
    }

    for (int t = 0; t < TT; ++t) {
        f32x4 aE[2] = {{0.f,0.f,0.f,0.f},{0.f,0.f,0.f,0.f}};
        f32x4 aO[2] = {{0.f,0.f,0.f,0.f},{0.f,0.f,0.f,0.f}};
        // x projection FIRST (independent of recurrence -> overlaps peers' publish)
        #pragma unroll
        for (int mt = 0; mt < 2; ++mt) {
            const float* xp = x + ((size_t)t * BB + mg * 32 + mt * 16 + r16) * CC + q8;
            #pragma unroll
            for (int kt = 0; kt < 8; ++kt) {
                float4 f0 = *(const float4*)(xp + kt * 32);
                float4 f1 = *(const float4*)(xp + kt * 32 + 4);
                bf16x8 a = pack8(f0, f1);
                if (kt & 1) aO[mt] = __builtin_amdgcn_mfma_f32_16x16x32_bf16(a, w[kt], aO[mt], 0, 0, 0);
                else        aE[mt] = __builtin_amdgcn_mfma_f32_16x16x32_bf16(a, w[kt], aE[mt], 0, 0, 0);
            }
        }
        {
            u32 need0 = t ? 8u * (u32)t : 0u;
            u32 need1 = (t >= RING) ? 8u * (u32)(t - RING + 1) : 0u;
            if (need0 | need1) poll2(cnt, need0, need1);
        }
        // stage h0[t-1] slice (32 rows) into LDS: coalesced agent loads
        {
            const u64* srcq = (const u64*)(h0r + (size_t)((t + RING - 1) & (RING - 1)) * S_ELEMS
                                           + (size_t)mg * 32 * HH);
            u64 sb[16];
            #pragma unroll
            for (int i = 0; i < 8; ++i) {
                int ch = i * 256 + tid;
                sb[2 * i]     = cload64(srcq + ch * 2);
                sb[2 * i + 1] = cload64(srcq + ch * 2 + 1);
            }
            #pragma unroll
            for (int i = 0; i < 8; ++i) {
                int ch = i * 256 + tid;
                u64* d = (u64*)&smem[(ch >> 6) * 520 + (ch & 63) * 8];
                d[0] = sb[2 * i]; d[1] = sb[2 * i + 1];
            }
        }
        __syncthreads();
        // recurrent MFMAs from LDS (shared by all 4 waves)
        #pragma unroll
        for (int kt = 0; kt < 16; ++kt)
            #pragma unroll
            for (int mt = 0; mt < 2; ++mt) {
                bf16x8 a = *(const bf16x8*)&smem[(mt * 16 + r16) * 520 + kt * 32 + q8];
                if (kt & 1) aO[mt] = __builtin_amdgcn_mfma_f32_16x16x32_bf16(a, w[8 + kt], aO[mt], 0, 0, 0);
                else        aE[mt] = __builtin_amdgcn_mfma_f32_16x16x32_bf16(a, w[8 + kt], aE[mt], 0, 0, 0);
            }
        // epilogue
        u16* hw = h0r + (size_t)(t & (RING - 1)) * S_ELEMS;
        #pragma unroll
        for (int mt = 0; mt < 2; ++mt) {
            f32x4 acc = aE[mt] + aO[mt];
            float h = lstm_cell(acc, sl0, sl1, sl2, sl3, gg, bi, bff, bgc, bo, c[mt]);
            int myb = mg * 32 + mt * 16 + quad * 4 + gg;
            u32 hb = (u32)f2b_rne(h);
            u32 v01 = hb | ((u32)__shfl_xor((int)hb, 1, 64) << 16);
            u32 v23 = (u32)__shfl_xor((int)v01, 2, 64);
            if (jj == 0)
                cstore64((u64*)(hw + (size_t)myb * HH + cg * 4), (u64)v01 | ((u64)v23 << 32));
            if (t == TT - 1) {
                float* fin = out + Y_ELEMS;
                fin[myb * HH + col] = h;
                fin[S_ELEMS + myb * HH + col] = c[mt];
            }
        }
        __syncthreads();  // drains all waves' vmcnt -> h stores at MALL
        if (tid == 0) cadd32(cnt + (bid >> 3) * 16, 1u);
    }
}

// ============================ layer 1 ======================================
__device__ void run_l1(const float* __restrict__ c0, float* __restrict__ out,
                       unsigned char* __restrict__ ws, int b2, u16* smem) {
    u32* cnt = (u32*)(ws + WS_CNT);
    const float* bs = (const float*)(ws + WS_BSUM1);
    const u16* h0r = (const u16*)(ws + WS_H0R);
    u16* h1r = (u16*)(ws + WS_H1R);
    const u16* wpk = (const u16*)(ws + WS_WPK1);

    const int tid = threadIdx.x, lane = tid & 63, wv = tid >> 6;
    const int mg = b2 & 1;
    const int cg = (b2 >> 1) * 4 + wv;
    const int r16 = lane & 15, quad = lane >> 4, q8 = quad * 8;
    const int gg = r16 >> 2, jj = r16 & 3;
    const int sl0 = (quad << 4) | jj, sl1 = sl0 | 4, sl2 = sl0 | 8, sl3 = sl0 | 12;
    const int col = cg * 4 + jj;
    const int TILE1 = 32 * 520;

    const float bi = bs[0 * HH + col], bff = bs[1 * HH + col];
    const float bgc = bs[2 * HH + col], bo = bs[3 * HH + col];
    float c[2];
    #pragma unroll
    for (int mt = 0; mt < 2; ++mt)
        c[mt] = c0[(mg * 32 + mt * 16 + quad * 4 + gg) * HH + col];

    bf16x8 w[32];
    {
        const u16* wp = wpk + (size_t)(cg * 32 * 64 + lane) * 8;
        #pragma unroll
        for (int kt = 0; kt < 32; ++kt) w[kt] = *(const bf16x8*)(wp + (size_t)kt * 64 * 8);
    }

    for (int t = 0; t < TT; ++t) {
        poll2(cnt, 8u * (u32)(t + 1), t ? 8u * (u32)t : 0u);
        // phase A: stage y0[t] slice (ring slot t%4) -> LDS tile 0
        {
            const u64* sy = (const u64*)(h0r + (size_t)(t & (RING - 1)) * S_ELEMS
                                         + (size_t)mg * 32 * HH);
            u64 sb[16];
            #pragma unroll
            for (int i = 0; i < 8; ++i) {
                int ch = i * 256 + tid;
                sb[2 * i]     = cload64(sy + ch * 2);
                sb[2 * i + 1] = cload64(sy + ch * 2 + 1);
            }
            #pragma unroll
            for (int i = 0; i < 8; ++i) {
                int ch = i * 256 + tid;
                u64* d = (u64*)&smem[(ch >> 6) * 520 + (ch & 63) * 8];
                d[0] = sb[2 * i]; d[1] = sb[2 * i + 1];
            }
        }
        // phase B: ISSUE h1[t-1] loads now; latency hides under y0 MFMAs
        u64 hc[16];
        {
            const u64* sh = (const u64*)(h1r + (size_t)((t + 1) & 1) * S_ELEMS
                                         + (size_t)mg * 32 * HH);
            #pragma unroll
            for (int i = 0; i < 8; ++i) {
                int ch = i * 256 + tid;
                hc[2 * i]     = cload64(sh + ch * 2);
                hc[2 * i + 1] = cload64(sh + ch * 2 + 1);
            }
        }
        __syncthreads();  // tile 0 visible
        f32x4 aE[2] = {{0.f,0.f,0.f,0.f},{0.f,0.f,0.f,0.f}};
        f32x4 aO[2] = {{0.f,0.f,0.f,0.f},{0.f,0.f,0.f,0.f}};
        #pragma unroll
        for (int kt = 0; kt < 16; ++kt)
            #pragma unroll
            for (int mt = 0; mt < 2; ++mt) {
                bf16x8 a = *(const bf16x8*)&smem[(mt * 16 + r16) * 520 + kt * 32 + q8];
                if (kt & 1) aO[mt] = __builtin_amdgcn_mfma_f32_16x16x32_bf16(a, w[kt], aO[mt], 0, 0, 0);
                else        aE[mt] = __builtin_amdgcn_mfma_f32_16x16x32_bf16(a, w[kt], aE[mt], 0, 0, 0);
            }
        // write h1 tile (loads have landed during the MFMAs)
        #pragma unroll
        for (int i = 0; i < 8; ++i) {
            int ch = i * 256 + tid;
            u64* d = (u64*)&smem[TILE1 + (ch >> 6) * 520 + (ch & 63) * 8];
            d[0] = hc[2 * i]; d[1] = hc[2 * i + 1];
        }
        __syncthreads();  // tile 1 visible
        #pragma unroll
        for (int kt = 0; kt < 16; ++kt)
            #pragma unroll
            for (int mt = 0; mt < 2; ++mt) {
                bf16x8 a = *(const bf16x8*)&smem[TILE1 + (mt * 16 + r16) * 520 + kt * 32 + q8];
                if (kt & 1) aO[mt] = __builtin_amdgcn_mfma_f32_16x16x32_bf16(a, w[16 + kt], aO[mt], 0, 0, 0);
                else        aE[mt] = __builtin_amdgcn_mfma_f32_16x16x32_bf16(a, w[16 + kt], aE[mt], 0, 0, 0);
            }
        // epilogue
        u16* hw = h1r + (size_t)(t & 1) * S_ELEMS;
        #pragma unroll
        for (int mt = 0; mt < 2; ++mt) {
            f32x4 acc = aE[mt] + aO[mt];
            float h = lstm_cell(acc, sl0, sl1, sl2, sl3, gg, bi, bff, bgc, bo, c[mt]);
            int myb = mg * 32 + mt * 16 + quad * 4 + gg;
            u32 hb = (u32)f2b_rne(h);
            u32 v01 = hb | ((u32)__shfl_xor((int)hb, 1, 64) << 16);
            u32 v23 = (u32)__shfl_xor((int)v01, 2, 64);
            if (jj == 0)
                cstore64((u64*)(hw + (size_t)myb * HH + cg * 4), (u64)v01 | ((u64)v23 << 32));
            out[(size_t)t * S_ELEMS + myb * HH + col] = h;
            if (t == TT - 1) {
                float* fin = out + Y_ELEMS + 2 * S_ELEMS;
                fin[myb * HH + col] = h;
                fin[S_ELEMS + myb * HH + col] = c[mt];
            }
        }
        __syncthreads();  // drains vmcnt -> h1 stores at MALL
        if (tid == 0) cadd32(cnt + (8 + (b2 >> 3)) * 16, 1u);
    }
}

__global__ __launch_bounds__(256, 1) void k_lstm(const float* __restrict__ x,
                                                 const float* __restrict__ c00,
                                                 const float* __restrict__ c01,
                                                 float* __restrict__ out,
                                                 unsigned char* __restrict__ ws) {
    __shared__ __align__(16) u16 smem[2][32][520];  // 133120 B > 80K -> 1 block/CU
    const int bid = blockIdx.x;
    if (bid < 64) run_l0(x, c00, out, ws, bid, &smem[0][0][0]);
    else          run_l1(c01, out, ws, bid - 64, &smem[0][0][0]);
}

extern "C" void kernel_launch(void* const* d_in, const int* in_sizes, int n_in,
                              void* d_out, int out_size, void* d_ws, size_t ws_size,
                              hipStream_t stream) {
    const float* x    = (const float*)d_in[0];
    const float* h0_0 = (const float*)d_in[1];
    const float* c0_0 = (const float*)d_in[2];
    const float* h0_1 = (const float*)d_in[3];
    const float* c0_1 = (const float*)d_in[4];
    const float* Wih0 = (const float*)d_in[5];
    const float* Whh0 = (const float*)d_in[6];
    const float* bih0 = (const float*)d_in[7];
    const float* bhh0 = (const float*)d_in[8];
    const float* Wih1 = (const float*)d_in[9];
    const float* Whh1 = (const float*)d_in[10];
    const float* bih1 = (const float*)d_in[11];
    const float* bhh1 = (const float*)d_in[12];
    float* out = (float*)d_out;
    unsigned char* ws = (unsigned char*)d_ws;

    k_init<<<128, 256, 0, stream>>>(bih0, bhh0, bih1, bhh1, h0_0, h0_1, ws);
    k_wprep<<<1792, 256, 0, stream>>>(Wih0, Whh0, Wih1, Whh1, ws);
    k_lstm<<<128, 256, 0, stream>>>(x, c0_0, c0_1, out, ws);
}